// Round 1
// baseline (1808.937 us; speedup 1.0000x reference)
//
#include <hip/hip_runtime.h>
#include <cstdint>
#include <cstddef>

// Problem constants (AltAttention: B=2, S=2048, D=1024, H=16, dh=64)
#define B_  2
#define S_  2048
#define D_  1024
#define H_  16
#define DH_ 64
#define M_  (B_*S_)     // 4096 rows
#define N3_ (3*D_)      // 3072 qkv cols

// ---------------------------------------------------------------------------
// Mask layout detection: harness may pass the bool mask as bytes, int32,
// int64, or float32. Distinguish by byte patterns in the first 4096 bytes
// (safe to read under every candidate layout: bool buffer is exactly 4096 B).
//  - any byte value >1            -> float32 (0x3f80.. pattern)
//  - nonzero byte at off%4 != 0   -> 1-byte elements (bool/uint8)
//  - nonzero byte at off%8 == 4   -> int32
//  - else                         -> int64
// ---------------------------------------------------------------------------
__global__ void k_detect_mask(const unsigned char* __restrict__ mb, int* __restrict__ flag) {
    __shared__ int sBig, sM4, sM8;
    if (threadIdx.x == 0) { sBig = 0; sM4 = 0; sM8 = 0; }
    __syncthreads();
    int big = 0, m4 = 0, m8 = 0;
    for (int i = threadIdx.x; i < 4096; i += blockDim.x) {
        unsigned char v = mb[i];
        if (v > 1) big = 1;
        if (v && (i & 3)) m4 = 1;
        if (v && ((i & 7) == 4)) m8 = 1;
    }
    if (big) atomicOr(&sBig, 1);
    if (m4)  atomicOr(&sM4, 1);
    if (m8)  atomicOr(&sM8, 1);
    __syncthreads();
    if (threadIdx.x == 0) {
        int w;
        if (sBig)      w = 0;  // float32
        else if (sM4)  w = 1;  // bytes
        else if (sM8)  w = 4;  // int32
        else           w = 8;  // int64
        *flag = w;
    }
}

__global__ void k_expand_mask(const void* __restrict__ mask, const int* __restrict__ flag,
                              float* __restrict__ maskbias, int n) {
    int i = blockIdx.x * blockDim.x + threadIdx.x;
    if (i >= n) return;
    int w = *flag;
    bool on;
    if (w == 0)      on = ((const float*)mask)[i] != 0.0f;
    else if (w == 1) on = ((const unsigned char*)mask)[i] != 0;
    else if (w == 4) on = ((const int*)mask)[i] != 0;
    else             on = ((const long long*)mask)[i] != 0;
    maskbias[i] = on ? 0.0f : -1e30f;
}

// ---------------------------------------------------------------------------
// fp32 GEMM: C[m][n] = sum_k A[m][k] * W[n][k] + bias[n]
// (both operands K-major "NT" layout — matches inputs@W.T with row-major W)
// 64x64 tile, BK=16, 256 threads, 4x4 microtile per thread.
// ---------------------------------------------------------------------------
__global__ __launch_bounds__(256) void k_gemm_nt_bias(
    const float* __restrict__ A, const float* __restrict__ W,
    const float* __restrict__ bias, float* __restrict__ C,
    int M, int N, int K) {
    __shared__ float As[64][20];   // [m][k], pad 16+4 keeps float4 alignment
    __shared__ float Ws[16][68];   // [k][n], pad 64+4

    const int tid = threadIdx.x;
    const int tx = tid & 15, ty = tid >> 4;
    const int m0 = blockIdx.y * 64, n0 = blockIdx.x * 64;
    const int lrow = tid >> 2;     // 0..63
    const int lvec = tid & 3;      // 0..3

    float acc[4][4] = {};

    for (int k0 = 0; k0 < K; k0 += 16) {
        float4 av = *reinterpret_cast<const float4*>(&A[(size_t)(m0 + lrow) * K + k0 + lvec * 4]);
        float4 wv = *reinterpret_cast<const float4*>(&W[(size_t)(n0 + lrow) * K + k0 + lvec * 4]);
        __syncthreads();   // previous iteration's reads done
        *reinterpret_cast<float4*>(&As[lrow][lvec * 4]) = av;
        Ws[lvec * 4 + 0][lrow] = wv.x;
        Ws[lvec * 4 + 1][lrow] = wv.y;
        Ws[lvec * 4 + 2][lrow] = wv.z;
        Ws[lvec * 4 + 3][lrow] = wv.w;
        __syncthreads();
#pragma unroll
        for (int kk = 0; kk < 16; ++kk) {
            float a0 = As[ty * 4 + 0][kk];
            float a1 = As[ty * 4 + 1][kk];
            float a2 = As[ty * 4 + 2][kk];
            float a3 = As[ty * 4 + 3][kk];
            float4 w4 = *reinterpret_cast<const float4*>(&Ws[kk][tx * 4]);
            acc[0][0] += a0 * w4.x; acc[0][1] += a0 * w4.y; acc[0][2] += a0 * w4.z; acc[0][3] += a0 * w4.w;
            acc[1][0] += a1 * w4.x; acc[1][1] += a1 * w4.y; acc[1][2] += a1 * w4.z; acc[1][3] += a1 * w4.w;
            acc[2][0] += a2 * w4.x; acc[2][1] += a2 * w4.y; acc[2][2] += a2 * w4.z; acc[2][3] += a2 * w4.w;
            acc[3][0] += a3 * w4.x; acc[3][1] += a3 * w4.y; acc[3][2] += a3 * w4.z; acc[3][3] += a3 * w4.w;
        }
    }

    float b0 = bias[n0 + tx * 4 + 0];
    float b1 = bias[n0 + tx * 4 + 1];
    float b2 = bias[n0 + tx * 4 + 2];
    float b3 = bias[n0 + tx * 4 + 3];
#pragma unroll
    for (int i = 0; i < 4; ++i) {
        float4 o;
        o.x = acc[i][0] + b0;
        o.y = acc[i][1] + b1;
        o.z = acc[i][2] + b2;
        o.w = acc[i][3] + b3;
        *reinterpret_cast<float4*>(&C[(size_t)(m0 + ty * 4 + i) * N + n0 + tx * 4]) = o;
    }
}

// ---------------------------------------------------------------------------
// Flash-style attention, fp32.
// Block = (b, h, 32 q-rows), 256 threads. K/V staged in 64-key LDS tiles.
// Thread t: q-row = t>>3, sub-lane = t&7 (8 scores per tile; 8 output dims).
// qkv layout: row m = b*S+s, head h: q at col h*192, k at +64, v at +128.
// score = (q·k)/32 - slope_h*|i-j| + maskbias[j];  slope_h = 2^(-0.5*(h+1))
// ---------------------------------------------------------------------------
__global__ __launch_bounds__(256) void k_attn(
    const float* __restrict__ qkv, const float* __restrict__ maskbias,
    float* __restrict__ x) {
    __shared__ float Ks[64][68];
    __shared__ float Vs[64][68];
    __shared__ float Qs[32][68];
    __shared__ float Ps[32][68];

    const int tid = threadIdx.x;
    const int nqt = S_ / 32;                     // 64 q-tiles
    const int qt = blockIdx.x % nqt;
    const int h  = (blockIdx.x / nqt) % H_;
    const int b  = blockIdx.x / (nqt * H_);
    const int q0 = qt * 32;
    const size_t rowbase = (size_t)b * S_ * N3_;
    const int hq = h * 192, hk = h * 192 + 64, hv = h * 192 + 128;

    // stage Q tile (32 rows x 64 dims)
    {
        int u = tid;
#pragma unroll
        for (int r = 0; r < 2; ++r) {
            int row = u >> 4, vec = u & 15;
            float4 v = *reinterpret_cast<const float4*>(
                &qkv[rowbase + (size_t)(q0 + row) * N3_ + hq + vec * 4]);
            *reinterpret_cast<float4*>(&Qs[row][vec * 4]) = v;
            u += 256;
        }
    }
    __syncthreads();

    const int row = tid >> 3;   // 0..31
    const int sub = tid & 7;    // 0..7
    float4 qreg[16];
#pragma unroll
    for (int i = 0; i < 16; ++i)
        qreg[i] = *reinterpret_cast<const float4*>(&Qs[row][i * 4]);

    float m = -1e30f, l = 0.0f;
    float acc[8] = {};
    const float scale = 0.03125f;                       // D^-0.5 = 1/32
    const float slope = exp2f(-0.5f * (float)(h + 1));  // alibi slope
    const int qg = q0 + row;
    const int dbase = sub * 8;

    for (int k0 = 0; k0 < S_; k0 += 64) {
        __syncthreads();   // prev tile's Vs/Ps reads complete
        // stage K,V tiles: 64 rows x 16 float4 each
#pragma unroll
        for (int r = 0; r < 4; ++r) {
            int u = tid + r * 256;
            int krow = u >> 4, vec = u & 15;
            size_t base = rowbase + (size_t)(k0 + krow) * N3_;
            *reinterpret_cast<float4*>(&Ks[krow][vec * 4]) =
                *reinterpret_cast<const float4*>(&qkv[base + hk + vec * 4]);
            *reinterpret_cast<float4*>(&Vs[krow][vec * 4]) =
                *reinterpret_cast<const float4*>(&qkv[base + hv + vec * 4]);
        }
        __syncthreads();

        // scores: 8 keys per thread (j = sub + 8*jj)
        float s[8];
#pragma unroll
        for (int jj = 0; jj < 8; ++jj) {
            int j = sub + jj * 8;
            float dot = 0.0f;
#pragma unroll
            for (int dv = 0; dv < 16; ++dv) {
                float4 kv = *reinterpret_cast<const float4*>(&Ks[j][dv * 4]);
                dot += qreg[dv].x * kv.x + qreg[dv].y * kv.y
                     + qreg[dv].z * kv.z + qreg[dv].w * kv.w;
            }
            int kg = k0 + j;
            float bias = maskbias[b * S_ + kg];
            float ad = fabsf((float)(qg - kg));
            s[jj] = dot * scale - slope * ad + bias;
        }

        // online softmax (per q-row = 8 consecutive lanes)
        float tmax = s[0];
#pragma unroll
        for (int jj = 1; jj < 8; ++jj) tmax = fmaxf(tmax, s[jj]);
#pragma unroll
        for (int off = 1; off < 8; off <<= 1)
            tmax = fmaxf(tmax, __shfl_xor(tmax, off));
        float mnew = fmaxf(m, tmax);
        float c = __expf(m - mnew);
        float psum = 0.0f;
#pragma unroll
        for (int jj = 0; jj < 8; ++jj) {
            float p = __expf(s[jj] - mnew);
            Ps[row][sub + jj * 8] = p;
            psum += p;
        }
#pragma unroll
        for (int off = 1; off < 8; off <<= 1)
            psum += __shfl_xor(psum, off);
        l = l * c + psum;
        m = mnew;
#pragma unroll
        for (int i = 0; i < 8; ++i) acc[i] *= c;
        __syncthreads();   // Ps visible to the whole row group

        // PV accumulate: thread owns dims [dbase, dbase+8)
#pragma unroll
        for (int j = 0; j < 64; ++j) {
            float p = Ps[row][j];
            float4 v0 = *reinterpret_cast<const float4*>(&Vs[j][dbase]);
            float4 v1 = *reinterpret_cast<const float4*>(&Vs[j][dbase + 4]);
            acc[0] += p * v0.x; acc[1] += p * v0.y; acc[2] += p * v0.z; acc[3] += p * v0.w;
            acc[4] += p * v1.x; acc[5] += p * v1.y; acc[6] += p * v1.z; acc[7] += p * v1.w;
        }
    }

    float inv = 1.0f / l;
    float4 o0, o1;
    o0.x = acc[0] * inv; o0.y = acc[1] * inv; o0.z = acc[2] * inv; o0.w = acc[3] * inv;
    o1.x = acc[4] * inv; o1.y = acc[5] * inv; o1.z = acc[6] * inv; o1.w = acc[7] * inv;
    size_t xoff = ((size_t)b * S_ + qg) * D_ + h * 64 + dbase;
    *reinterpret_cast<float4*>(&x[xoff])     = o0;
    *reinterpret_cast<float4*>(&x[xoff + 4]) = o1;
}

// ---------------------------------------------------------------------------
extern "C" void kernel_launch(void* const* d_in, const int* in_sizes, int n_in,
                              void* d_out, int out_size, void* d_ws, size_t ws_size,
                              hipStream_t stream) {
    const float* inputs = (const float*)d_in[0];
    const void*  mask   = d_in[1];
    const float* Wqkv   = (const float*)d_in[2];
    const float* bqkv   = (const float*)d_in[3];
    const float* Wproj  = (const float*)d_in[4];
    const float* bproj  = (const float*)d_in[5];
    float* out = (float*)d_out;

    // workspace layout (floats): qkv | x | maskbias | flag
    float* qkv      = (float*)d_ws;                   // M_*N3_ = 12.58M floats
    float* x        = qkv + (size_t)M_ * N3_;         // M_*D_
    float* maskbias = x + (size_t)M_ * D_;            // M_
    int*   flag     = (int*)(maskbias + M_);

    k_detect_mask<<<1, 256, 0, stream>>>((const unsigned char*)mask, flag);
    k_expand_mask<<<(M_ + 255) / 256, 256, 0, stream>>>(mask, flag, maskbias, M_);

    dim3 g1(N3_ / 64, M_ / 64);   // 48 x 64
    k_gemm_nt_bias<<<g1, 256, 0, stream>>>(inputs, Wqkv, bqkv, qkv, M_, N3_, D_);

    k_attn<<<B_ * H_ * (S_ / 32), 256, 0, stream>>>(qkv, maskbias, x);

    dim3 g2(D_ / 64, M_ / 64);    // 16 x 64
    k_gemm_nt_bias<<<g2, 256, 0, stream>>>(x, Wproj, bproj, out, M_, D_, D_);
}

// Round 2
// 731.446 us; speedup vs baseline: 2.4731x; 2.4731x over previous
//
#include <hip/hip_runtime.h>
#include <cstdint>
#include <cstddef>

// Problem constants (AltAttention: B=2, S=2048, D=1024, H=16, dh=64)
#define B_  2
#define S_  2048
#define D_  1024
#define H_  16
#define DH_ 64
#define M_  (B_*S_)     // 4096 rows
#define N3_ (3*D_)      // 3072 qkv cols

typedef float f32x4 __attribute__((ext_vector_type(4)));
typedef short short8 __attribute__((ext_vector_type(8)));
typedef unsigned short u16x8 __attribute__((ext_vector_type(8)));
typedef unsigned short u16x4 __attribute__((ext_vector_type(4)));

__device__ __forceinline__ unsigned short f2bf(float x) {
    unsigned int u = __float_as_uint(x);
    unsigned int r = (u + 0x7FFFu + ((u >> 16) & 1u)) >> 16;
    return (unsigned short)r;
}

// ---------------------------------------------------------------------------
// Mask layout detection (unchanged from round 1 — it passed).
// ---------------------------------------------------------------------------
__global__ void k_detect_mask(const unsigned char* __restrict__ mb, int* __restrict__ flag) {
    __shared__ int sBig, sM4, sM8;
    if (threadIdx.x == 0) { sBig = 0; sM4 = 0; sM8 = 0; }
    __syncthreads();
    int big = 0, m4 = 0, m8 = 0;
    for (int i = threadIdx.x; i < 4096; i += blockDim.x) {
        unsigned char v = mb[i];
        if (v > 1) big = 1;
        if (v && (i & 3)) m4 = 1;
        if (v && ((i & 7) == 4)) m8 = 1;
    }
    if (big) atomicOr(&sBig, 1);
    if (m4)  atomicOr(&sM4, 1);
    if (m8)  atomicOr(&sM8, 1);
    __syncthreads();
    if (threadIdx.x == 0) {
        int w;
        if (sBig)      w = 0;  // float32
        else if (sM4)  w = 1;  // bytes
        else if (sM8)  w = 4;  // int32
        else           w = 8;  // int64
        *flag = w;
    }
}

__global__ void k_expand_mask(const void* __restrict__ mask, const int* __restrict__ flag,
                              float* __restrict__ maskbias, int n) {
    int i = blockIdx.x * blockDim.x + threadIdx.x;
    if (i >= n) return;
    int w = *flag;
    bool on;
    if (w == 0)      on = ((const float*)mask)[i] != 0.0f;
    else if (w == 1) on = ((const unsigned char*)mask)[i] != 0;
    else if (w == 4) on = ((const int*)mask)[i] != 0;
    else             on = ((const long long*)mask)[i] != 0;
    maskbias[i] = on ? 0.0f : -1e30f;
}

// ---------------------------------------------------------------------------
// fp32 GEMM (unchanged): C[m][n] = sum_k A[m][k]*W[n][k] + bias[n]
// ---------------------------------------------------------------------------
__global__ __launch_bounds__(256) void k_gemm_nt_bias(
    const float* __restrict__ A, const float* __restrict__ W,
    const float* __restrict__ bias, float* __restrict__ C,
    int M, int N, int K) {
    __shared__ float As[64][20];
    __shared__ float Ws[16][68];

    const int tid = threadIdx.x;
    const int tx = tid & 15, ty = tid >> 4;
    const int m0 = blockIdx.y * 64, n0 = blockIdx.x * 64;
    const int lrow = tid >> 2;
    const int lvec = tid & 3;

    float acc[4][4] = {};

    for (int k0 = 0; k0 < K; k0 += 16) {
        float4 av = *reinterpret_cast<const float4*>(&A[(size_t)(m0 + lrow) * K + k0 + lvec * 4]);
        float4 wv = *reinterpret_cast<const float4*>(&W[(size_t)(n0 + lrow) * K + k0 + lvec * 4]);
        __syncthreads();
        *reinterpret_cast<float4*>(&As[lrow][lvec * 4]) = av;
        Ws[lvec * 4 + 0][lrow] = wv.x;
        Ws[lvec * 4 + 1][lrow] = wv.y;
        Ws[lvec * 4 + 2][lrow] = wv.z;
        Ws[lvec * 4 + 3][lrow] = wv.w;
        __syncthreads();
#pragma unroll
        for (int kk = 0; kk < 16; ++kk) {
            float a0 = As[ty * 4 + 0][kk];
            float a1 = As[ty * 4 + 1][kk];
            float a2 = As[ty * 4 + 2][kk];
            float a3 = As[ty * 4 + 3][kk];
            float4 w4 = *reinterpret_cast<const float4*>(&Ws[kk][tx * 4]);
            acc[0][0] += a0 * w4.x; acc[0][1] += a0 * w4.y; acc[0][2] += a0 * w4.z; acc[0][3] += a0 * w4.w;
            acc[1][0] += a1 * w4.x; acc[1][1] += a1 * w4.y; acc[1][2] += a1 * w4.z; acc[1][3] += a1 * w4.w;
            acc[2][0] += a2 * w4.x; acc[2][1] += a2 * w4.y; acc[2][2] += a2 * w4.z; acc[2][3] += a2 * w4.w;
            acc[3][0] += a3 * w4.x; acc[3][1] += a3 * w4.y; acc[3][2] += a3 * w4.z; acc[3][3] += a3 * w4.w;
        }
    }

    float b0 = bias[n0 + tx * 4 + 0];
    float b1 = bias[n0 + tx * 4 + 1];
    float b2 = bias[n0 + tx * 4 + 2];
    float b3 = bias[n0 + tx * 4 + 3];
#pragma unroll
    for (int i = 0; i < 4; ++i) {
        float4 o;
        o.x = acc[i][0] + b0;
        o.y = acc[i][1] + b1;
        o.z = acc[i][2] + b2;
        o.w = acc[i][3] + b3;
        *reinterpret_cast<float4*>(&C[(size_t)(m0 + ty * 4 + i) * N + n0 + tx * 4]) = o;
    }
}

// ---------------------------------------------------------------------------
// Flash attention with bf16 MFMA (mfma_f32_16x16x32_bf16).
// Block = (b, h, 64 q-rows), 4 waves; wave owns 16 q-rows. K-tile = 64 keys.
// Layouts (m89-verified):
//   A frag: row = lane&15, k = (lane>>4)*8 + j  (8 consecutive k -> b128)
//   B frag: col = lane&15, k = (lane>>4)*8 + j
//   C frag: col = lane&15, row = (lane>>4)*4 + reg
// LDS: Kt[key][dh] bf16 (pad 72 -> 144B row, 16B-aligned, 2-way banks = free)
//      Vt[dh][key] bf16 (transposed during staging via 4x4 register blocks)
//      QP[q][dh]   bf16 (Q staging, then reused per-wave as P strip [q][key])
// ---------------------------------------------------------------------------
__global__ __launch_bounds__(256) void k_attn_mfma(
    const float* __restrict__ qkv, const float* __restrict__ maskbias,
    float* __restrict__ x) {
    __shared__ __align__(16) unsigned short Kt[64][72];
    __shared__ __align__(16) unsigned short Vt[64][72];
    __shared__ __align__(16) unsigned short QP[64][72];

    const int tid  = threadIdx.x;
    const int lane = tid & 63;
    const int wq   = tid >> 6;            // wave 0..3 -> q-strip
    const int g    = lane >> 4;           // k-group 0..3
    const int l16  = lane & 15;

    const int nqt = S_ / 64;              // 32 q-tiles
    const int qt = blockIdx.x % nqt;
    const int h  = (blockIdx.x / nqt) % H_;
    const int b  = blockIdx.x / (nqt * H_);
    const int q0 = qt * 64;
    const size_t rowbase = (size_t)b * S_ * N3_;
    const int hq = h * 192, hk = hq + 64, hv = hq + 128;

    // ---- stage Q tile (64 x 64) as bf16
    {
        const int row = tid >> 2, cb = (tid & 3) * 16;
        const float* src = &qkv[rowbase + (size_t)(q0 + row) * N3_ + hq + cb];
        unsigned short tmp[16];
#pragma unroll
        for (int i = 0; i < 4; ++i) {
            float4 v = *reinterpret_cast<const float4*>(src + i * 4);
            tmp[i*4+0] = f2bf(v.x); tmp[i*4+1] = f2bf(v.y);
            tmp[i*4+2] = f2bf(v.z); tmp[i*4+3] = f2bf(v.w);
        }
        *reinterpret_cast<u16x8*>(&QP[row][cb])     = *reinterpret_cast<u16x8*>(&tmp[0]);
        *reinterpret_cast<u16x8*>(&QP[row][cb + 8]) = *reinterpret_cast<u16x8*>(&tmp[8]);
    }
    __syncthreads();

    // ---- Q A-fragments (dh halves 0..31, 32..63), kept in registers
    const short8 qa0 = *reinterpret_cast<const short8*>(&QP[wq*16 + l16][g*8]);
    const short8 qa1 = *reinterpret_cast<const short8*>(&QP[wq*16 + l16][32 + g*8]);

    f32x4 Oacc[4];
#pragma unroll
    for (int df = 0; df < 4; ++df) Oacc[df] = (f32x4){0.f, 0.f, 0.f, 0.f};
    float mrow[4] = {-1e30f, -1e30f, -1e30f, -1e30f};
    float lrow[4] = {0.f, 0.f, 0.f, 0.f};

    const float scale = 0.03125f;                        // D^-0.5
    const float slope = exp2f(-0.5f * (float)(h + 1));   // alibi

    for (int k0 = 0; k0 < S_; k0 += 64) {
        __syncthreads();   // prior tile's Kt/Vt reads complete

        // ---- stage K tile row-major bf16
        {
            const int row = tid >> 2, cb = (tid & 3) * 16;
            const float* src = &qkv[rowbase + (size_t)(k0 + row) * N3_ + hk + cb];
            unsigned short tmp[16];
#pragma unroll
            for (int i = 0; i < 4; ++i) {
                float4 v = *reinterpret_cast<const float4*>(src + i * 4);
                tmp[i*4+0] = f2bf(v.x); tmp[i*4+1] = f2bf(v.y);
                tmp[i*4+2] = f2bf(v.z); tmp[i*4+3] = f2bf(v.w);
            }
            *reinterpret_cast<u16x8*>(&Kt[row][cb])     = *reinterpret_cast<u16x8*>(&tmp[0]);
            *reinterpret_cast<u16x8*>(&Kt[row][cb + 8]) = *reinterpret_cast<u16x8*>(&tmp[8]);
        }
        // ---- stage V tile transposed: Vt[dim][key], 4x4 register transpose
        {
            const int kb = (tid & 15) * 4;
            const int db = (tid >> 4) * 4;
            const float* vsrc = &qkv[rowbase + (size_t)(k0 + kb) * N3_ + hv + db];
            float4 r0 = *reinterpret_cast<const float4*>(vsrc);
            float4 r1 = *reinterpret_cast<const float4*>(vsrc + N3_);
            float4 r2 = *reinterpret_cast<const float4*>(vsrc + 2 * N3_);
            float4 r3 = *reinterpret_cast<const float4*>(vsrc + 3 * N3_);
            u16x4 w0 = { f2bf(r0.x), f2bf(r1.x), f2bf(r2.x), f2bf(r3.x) };
            u16x4 w1 = { f2bf(r0.y), f2bf(r1.y), f2bf(r2.y), f2bf(r3.y) };
            u16x4 w2 = { f2bf(r0.z), f2bf(r1.z), f2bf(r2.z), f2bf(r3.z) };
            u16x4 w3 = { f2bf(r0.w), f2bf(r1.w), f2bf(r2.w), f2bf(r3.w) };
            *reinterpret_cast<u16x4*>(&Vt[db + 0][kb]) = w0;
            *reinterpret_cast<u16x4*>(&Vt[db + 1][kb]) = w1;
            *reinterpret_cast<u16x4*>(&Vt[db + 2][kb]) = w2;
            *reinterpret_cast<u16x4*>(&Vt[db + 3][kb]) = w3;
        }
        __syncthreads();

        // ---- QK^T: 4 key-fragments x 2 dh-halves
        f32x4 S[4];
#pragma unroll
        for (int jb = 0; jb < 4; ++jb) {
            short8 kb0 = *reinterpret_cast<const short8*>(&Kt[jb*16 + l16][g*8]);
            short8 kb1 = *reinterpret_cast<const short8*>(&Kt[jb*16 + l16][32 + g*8]);
            f32x4 c = (f32x4){0.f, 0.f, 0.f, 0.f};
            c = __builtin_amdgcn_mfma_f32_16x16x32_bf16(qa0, kb0, c, 0, 0, 0);
            c = __builtin_amdgcn_mfma_f32_16x16x32_bf16(qa1, kb1, c, 0, 0, 0);
            S[jb] = c;
        }

        // ---- ALiBi + mask + online softmax (rows live in 16-lane groups)
        float sc[4][4];  // [jb][reg]
#pragma unroll
        for (int jb = 0; jb < 4; ++jb) {
            const int kg = k0 + jb * 16 + l16;
            const float mb = maskbias[b * S_ + kg];
#pragma unroll
            for (int r = 0; r < 4; ++r) {
                const int qg = q0 + wq * 16 + g * 4 + r;
                int ad = qg - kg; ad = ad < 0 ? -ad : ad;
                sc[jb][r] = S[jb][r] * scale - slope * (float)ad + mb;
            }
        }
#pragma unroll
        for (int r = 0; r < 4; ++r) {
            float mx = fmaxf(fmaxf(sc[0][r], sc[1][r]), fmaxf(sc[2][r], sc[3][r]));
#pragma unroll
            for (int off = 1; off < 16; off <<= 1)
                mx = fmaxf(mx, __shfl_xor(mx, off));
            const float mn = fmaxf(mrow[r], mx);
            const float cr = __expf(mrow[r] - mn);
            mrow[r] = mn;
            float ps = 0.f;
#pragma unroll
            for (int jb = 0; jb < 4; ++jb) {
                float p = __expf(sc[jb][r] - mn);
                sc[jb][r] = p;
                ps += p;
            }
#pragma unroll
            for (int off = 1; off < 16; off <<= 1)
                ps += __shfl_xor(ps, off);
            lrow[r] = lrow[r] * cr + ps;
#pragma unroll
            for (int df = 0; df < 4; ++df) Oacc[df][r] *= cr;
            // P strip (per-wave region of QP; same-wave read below -> no barrier)
#pragma unroll
            for (int jb = 0; jb < 4; ++jb)
                QP[wq*16 + g*4 + r][jb*16 + l16] = f2bf(sc[jb][r]);
        }

        // ---- PV: A = P (keys as k), B = Vt
        const short8 pa0 = *reinterpret_cast<const short8*>(&QP[wq*16 + l16][g*8]);
        const short8 pa1 = *reinterpret_cast<const short8*>(&QP[wq*16 + l16][32 + g*8]);
#pragma unroll
        for (int df = 0; df < 4; ++df) {
            short8 vb0 = *reinterpret_cast<const short8*>(&Vt[df*16 + l16][g*8]);
            short8 vb1 = *reinterpret_cast<const short8*>(&Vt[df*16 + l16][32 + g*8]);
            Oacc[df] = __builtin_amdgcn_mfma_f32_16x16x32_bf16(pa0, vb0, Oacc[df], 0, 0, 0);
            Oacc[df] = __builtin_amdgcn_mfma_f32_16x16x32_bf16(pa1, vb1, Oacc[df], 0, 0, 0);
        }
    }

    // ---- normalize + store
    float inv[4];
#pragma unroll
    for (int r = 0; r < 4; ++r) inv[r] = 1.0f / lrow[r];
#pragma unroll
    for (int df = 0; df < 4; ++df) {
#pragma unroll
        for (int r = 0; r < 4; ++r) {
            const int qg = q0 + wq * 16 + g * 4 + r;
            x[(size_t)(b * S_ + qg) * D_ + h * 64 + df * 16 + l16] = Oacc[df][r] * inv[r];
        }
    }
}

// ---------------------------------------------------------------------------
extern "C" void kernel_launch(void* const* d_in, const int* in_sizes, int n_in,
                              void* d_out, int out_size, void* d_ws, size_t ws_size,
                              hipStream_t stream) {
    const float* inputs = (const float*)d_in[0];
    const void*  mask   = d_in[1];
    const float* Wqkv   = (const float*)d_in[2];
    const float* bqkv   = (const float*)d_in[3];
    const float* Wproj  = (const float*)d_in[4];
    const float* bproj  = (const float*)d_in[5];
    float* out = (float*)d_out;

    // workspace layout (floats): qkv | x | maskbias | flag
    float* qkv      = (float*)d_ws;                   // M_*N3_
    float* x        = qkv + (size_t)M_ * N3_;         // M_*D_
    float* maskbias = x + (size_t)M_ * D_;            // M_
    int*   flag     = (int*)(maskbias + M_);

    k_detect_mask<<<1, 256, 0, stream>>>((const unsigned char*)mask, flag);
    k_expand_mask<<<(M_ + 255) / 256, 256, 0, stream>>>(mask, flag, maskbias, M_);

    dim3 g1(N3_ / 64, M_ / 64);   // 48 x 64
    k_gemm_nt_bias<<<g1, 256, 0, stream>>>(inputs, Wqkv, bqkv, qkv, M_, N3_, D_);

    k_attn_mfma<<<B_ * H_ * (S_ / 64), 256, 0, stream>>>(qkv, maskbias, x);

    dim3 g2(D_ / 64, M_ / 64);    // 16 x 64
    k_gemm_nt_bias<<<g2, 256, 0, stream>>>(x, Wproj, bproj, out, M_, D_, D_);
}

// Round 3
// 235.027 us; speedup vs baseline: 7.6967x; 3.1122x over previous
//
#include <hip/hip_runtime.h>
#include <cstdint>
#include <cstddef>

// Problem constants (AltAttention: B=2, S=2048, D=1024, H=16, dh=64)
#define B_  2
#define S_  2048
#define D_  1024
#define H_  16
#define DH_ 64
#define M_  (B_*S_)     // 4096 rows
#define N3_ (3*D_)      // 3072 qkv cols

typedef float f32x4 __attribute__((ext_vector_type(4)));
typedef short short8 __attribute__((ext_vector_type(8)));
typedef unsigned short u16x8 __attribute__((ext_vector_type(8)));
typedef unsigned short u16x4 __attribute__((ext_vector_type(4)));

__device__ __forceinline__ unsigned short f2bf(float x) {
    unsigned int u = __float_as_uint(x);
    unsigned int r = (u + 0x7FFFu + ((u >> 16) & 1u)) >> 16;
    return (unsigned short)r;
}

__device__ __forceinline__ void gload16(const void* g, void* l) {
    __builtin_amdgcn_global_load_lds(
        (const __attribute__((address_space(1))) unsigned int*)g,
        (__attribute__((address_space(3))) unsigned int*)l,
        16, 0, 0);
}

// ---------------------------------------------------------------------------
// Mask layout detection + expansion (unchanged — verified rounds 1-2)
// ---------------------------------------------------------------------------
__global__ void k_detect_mask(const unsigned char* __restrict__ mb, int* __restrict__ flag) {
    __shared__ int sBig, sM4, sM8;
    if (threadIdx.x == 0) { sBig = 0; sM4 = 0; sM8 = 0; }
    __syncthreads();
    int big = 0, m4 = 0, m8 = 0;
    for (int i = threadIdx.x; i < 4096; i += blockDim.x) {
        unsigned char v = mb[i];
        if (v > 1) big = 1;
        if (v && (i & 3)) m4 = 1;
        if (v && ((i & 7) == 4)) m8 = 1;
    }
    if (big) atomicOr(&sBig, 1);
    if (m4)  atomicOr(&sM4, 1);
    if (m8)  atomicOr(&sM8, 1);
    __syncthreads();
    if (threadIdx.x == 0) {
        int w;
        if (sBig)      w = 0;
        else if (sM4)  w = 1;
        else if (sM8)  w = 4;
        else           w = 8;
        *flag = w;
    }
}

__global__ void k_expand_mask(const void* __restrict__ mask, const int* __restrict__ flag,
                              float* __restrict__ maskbias, int n) {
    int i = blockIdx.x * blockDim.x + threadIdx.x;
    if (i >= n) return;
    int w = *flag;
    bool on;
    if (w == 0)      on = ((const float*)mask)[i] != 0.0f;
    else if (w == 1) on = ((const unsigned char*)mask)[i] != 0;
    else if (w == 4) on = ((const int*)mask)[i] != 0;
    else             on = ((const long long*)mask)[i] != 0;
    maskbias[i] = on ? 0.0f : -1e30f;
}

// ---------------------------------------------------------------------------
// fp32 -> bf16 convert (vectorized, n % 4 == 0)
// ---------------------------------------------------------------------------
__global__ void k_f2bf(const float* __restrict__ in, unsigned short* __restrict__ out, int n) {
    int i = (blockIdx.x * blockDim.x + threadIdx.x) * 4;
    if (i >= n) return;
    float4 v = *reinterpret_cast<const float4*>(&in[i]);
    u16x4 o = { f2bf(v.x), f2bf(v.y), f2bf(v.z), f2bf(v.w) };
    *reinterpret_cast<u16x4*>(&out[i]) = o;
}

// ---------------------------------------------------------------------------
// bf16 MFMA GEMM (m97 structure): C[m][n] = sum_k A[m][k]*W[n][k] + bias[n]
// A: [M][K] bf16, W: [N][K] bf16. 128x128 tile, BK=64, 4 waves (2x2),
// global_load_lds width 16, 2-barrier K-loop, 16x16x32 bf16 MFMA.
// OUT_BF16 ? C is ushort(bf16) : C is float.
// ---------------------------------------------------------------------------
template <bool OUT_BF16>
__global__ __launch_bounds__(256) void k_gemm_bf16_nt(
    const unsigned short* __restrict__ A, const unsigned short* __restrict__ W,
    const float* __restrict__ bias, void* __restrict__ Cout,
    int M, int N, int K) {
    __shared__ __align__(16) unsigned short Al[128 * 64];
    __shared__ __align__(16) unsigned short Wl[128 * 64];

    const int tid  = threadIdx.x;
    const int lane = tid & 63;
    const int w    = tid >> 6;
    const int wr   = w >> 1, wc = w & 1;
    const int l16  = lane & 15, g = lane >> 4;
    const int m0 = blockIdx.y * 128, n0 = blockIdx.x * 128;

    f32x4 acc[4][4];
#pragma unroll
    for (int m = 0; m < 4; ++m)
#pragma unroll
        for (int n = 0; n < 4; ++n) acc[m][n] = (f32x4){0.f, 0.f, 0.f, 0.f};

    // staging geometry: chunk c = i*256 + tid covers tile row c>>3, cols ((c&7)*8..+8)
    const int srow = tid >> 3, scol = (tid & 7) * 8;

    for (int k0 = 0; k0 < K; k0 += 64) {
        __syncthreads();   // prior iteration's ds_reads complete
#pragma unroll
        for (int i = 0; i < 4; ++i) {
            const int c = i * 256 + tid;
            const int row = srow + i * 32;           // (i*256+tid)>>3
            gload16(A + (size_t)(m0 + row) * K + k0 + scol, Al + c * 8);
            gload16(W + (size_t)(n0 + row) * K + k0 + scol, Wl + c * 8);
        }
        __syncthreads();   // vmcnt(0) drain (compiler-inserted before barrier)

#pragma unroll
        for (int kk = 0; kk < 2; ++kk) {
            short8 a[4], b[4];
#pragma unroll
            for (int m = 0; m < 4; ++m)
                a[m] = *reinterpret_cast<const short8*>(
                    &Al[(size_t)(wr * 64 + m * 16 + l16) * 64 + kk * 32 + g * 8]);
#pragma unroll
            for (int n = 0; n < 4; ++n)
                b[n] = *reinterpret_cast<const short8*>(
                    &Wl[(size_t)(wc * 64 + n * 16 + l16) * 64 + kk * 32 + g * 8]);
#pragma unroll
            for (int m = 0; m < 4; ++m)
#pragma unroll
                for (int n = 0; n < 4; ++n)
                    acc[m][n] = __builtin_amdgcn_mfma_f32_16x16x32_bf16(a[m], b[n], acc[m][n], 0, 0, 0);
        }
    }

    // epilogue: C row = m*16 + g*4 + r, col = n*16 + l16 (m89-verified C layout)
    float bv[4];
#pragma unroll
    for (int n = 0; n < 4; ++n) bv[n] = bias[n0 + wc * 64 + n * 16 + l16];
#pragma unroll
    for (int m = 0; m < 4; ++m) {
#pragma unroll
        for (int r = 0; r < 4; ++r) {
            const size_t row = m0 + wr * 64 + m * 16 + g * 4 + r;
#pragma unroll
            for (int n = 0; n < 4; ++n) {
                const int col = n0 + wc * 64 + n * 16 + l16;
                float v = acc[m][n][r] + bv[n];
                if (OUT_BF16)
                    ((unsigned short*)Cout)[row * N + col] = f2bf(v);
                else
                    ((float*)Cout)[row * N + col] = v;
            }
        }
    }
}

// ---------------------------------------------------------------------------
// Flash attention, bf16 MFMA, bf16 I/O.
// Block = (b, h, 64 q-rows), 4 waves; wave owns 16 q-rows. K-tile = 64 keys.
// ---------------------------------------------------------------------------
__global__ __launch_bounds__(256) void k_attn_mfma(
    const unsigned short* __restrict__ qkv, const float* __restrict__ maskbias,
    unsigned short* __restrict__ x) {
    __shared__ __align__(16) unsigned short Kt[64][72];
    __shared__ __align__(16) unsigned short Vt[64][72];
    __shared__ __align__(16) unsigned short QP[64][72];

    const int tid  = threadIdx.x;
    const int lane = tid & 63;
    const int wq   = tid >> 6;
    const int g    = lane >> 4;
    const int l16  = lane & 15;

    const int nqt = S_ / 64;
    const int qt = blockIdx.x % nqt;
    const int h  = (blockIdx.x / nqt) % H_;
    const int b  = blockIdx.x / (nqt * H_);
    const int q0 = qt * 64;
    const size_t rowbase = (size_t)b * S_ * N3_;
    const int hq = h * 192, hk = hq + 64, hv = hq + 128;

    // ---- stage Q tile (64 x 64) bf16 copy
    {
        const int row = tid >> 2, cb = (tid & 3) * 16;
        const unsigned short* src = &qkv[rowbase + (size_t)(q0 + row) * N3_ + hq + cb];
        *reinterpret_cast<u16x8*>(&QP[row][cb])     = *reinterpret_cast<const u16x8*>(src);
        *reinterpret_cast<u16x8*>(&QP[row][cb + 8]) = *reinterpret_cast<const u16x8*>(src + 8);
    }
    __syncthreads();

    const short8 qa0 = *reinterpret_cast<const short8*>(&QP[wq*16 + l16][g*8]);
    const short8 qa1 = *reinterpret_cast<const short8*>(&QP[wq*16 + l16][32 + g*8]);

    f32x4 Oacc[4];
#pragma unroll
    for (int df = 0; df < 4; ++df) Oacc[df] = (f32x4){0.f, 0.f, 0.f, 0.f};
    float mrow[4] = {-1e30f, -1e30f, -1e30f, -1e30f};
    float lrow[4] = {0.f, 0.f, 0.f, 0.f};

    const float scale = 0.03125f;
    const float slope = exp2f(-0.5f * (float)(h + 1));

    for (int k0 = 0; k0 < S_; k0 += 64) {
        __syncthreads();

        // ---- stage K tile row-major (direct bf16 copy)
        {
            const int row = tid >> 2, cb = (tid & 3) * 16;
            const unsigned short* src = &qkv[rowbase + (size_t)(k0 + row) * N3_ + hk + cb];
            *reinterpret_cast<u16x8*>(&Kt[row][cb])     = *reinterpret_cast<const u16x8*>(src);
            *reinterpret_cast<u16x8*>(&Kt[row][cb + 8]) = *reinterpret_cast<const u16x8*>(src + 8);
        }
        // ---- stage V tile transposed via 4x4 blocks
        {
            const int kb = (tid & 15) * 4;
            const int db = (tid >> 4) * 4;
            const unsigned short* vsrc = &qkv[rowbase + (size_t)(k0 + kb) * N3_ + hv + db];
            u16x4 r0 = *reinterpret_cast<const u16x4*>(vsrc);
            u16x4 r1 = *reinterpret_cast<const u16x4*>(vsrc + N3_);
            u16x4 r2 = *reinterpret_cast<const u16x4*>(vsrc + 2 * N3_);
            u16x4 r3 = *reinterpret_cast<const u16x4*>(vsrc + 3 * N3_);
            u16x4 w0 = { r0.x, r1.x, r2.x, r3.x };
            u16x4 w1 = { r0.y, r1.y, r2.y, r3.y };
            u16x4 w2 = { r0.z, r1.z, r2.z, r3.z };
            u16x4 w3 = { r0.w, r1.w, r2.w, r3.w };
            *reinterpret_cast<u16x4*>(&Vt[db + 0][kb]) = w0;
            *reinterpret_cast<u16x4*>(&Vt[db + 1][kb]) = w1;
            *reinterpret_cast<u16x4*>(&Vt[db + 2][kb]) = w2;
            *reinterpret_cast<u16x4*>(&Vt[db + 3][kb]) = w3;
        }
        __syncthreads();

        // ---- QK^T
        f32x4 S[4];
#pragma unroll
        for (int jb = 0; jb < 4; ++jb) {
            short8 kb0 = *reinterpret_cast<const short8*>(&Kt[jb*16 + l16][g*8]);
            short8 kb1 = *reinterpret_cast<const short8*>(&Kt[jb*16 + l16][32 + g*8]);
            f32x4 c = (f32x4){0.f, 0.f, 0.f, 0.f};
            c = __builtin_amdgcn_mfma_f32_16x16x32_bf16(qa0, kb0, c, 0, 0, 0);
            c = __builtin_amdgcn_mfma_f32_16x16x32_bf16(qa1, kb1, c, 0, 0, 0);
            S[jb] = c;
        }

        // ---- ALiBi + mask + online softmax
        float sc[4][4];
#pragma unroll
        for (int jb = 0; jb < 4; ++jb) {
            const int kg = k0 + jb * 16 + l16;
            const float mb = maskbias[b * S_ + kg];
#pragma unroll
            for (int r = 0; r < 4; ++r) {
                const int qg = q0 + wq * 16 + g * 4 + r;
                int ad = qg - kg; ad = ad < 0 ? -ad : ad;
                sc[jb][r] = S[jb][r] * scale - slope * (float)ad + mb;
            }
        }
#pragma unroll
        for (int r = 0; r < 4; ++r) {
            float mx = fmaxf(fmaxf(sc[0][r], sc[1][r]), fmaxf(sc[2][r], sc[3][r]));
#pragma unroll
            for (int off = 1; off < 16; off <<= 1)
                mx = fmaxf(mx, __shfl_xor(mx, off));
            const float mn = fmaxf(mrow[r], mx);
            const float cr = __expf(mrow[r] - mn);
            mrow[r] = mn;
            float ps = 0.f;
#pragma unroll
            for (int jb = 0; jb < 4; ++jb) {
                float p = __expf(sc[jb][r] - mn);
                sc[jb][r] = p;
                ps += p;
            }
#pragma unroll
            for (int off = 1; off < 16; off <<= 1)
                ps += __shfl_xor(ps, off);
            lrow[r] = lrow[r] * cr + ps;
#pragma unroll
            for (int df = 0; df < 4; ++df) Oacc[df][r] *= cr;
#pragma unroll
            for (int jb = 0; jb < 4; ++jb)
                QP[wq*16 + g*4 + r][jb*16 + l16] = f2bf(sc[jb][r]);
        }

        // ---- PV
        const short8 pa0 = *reinterpret_cast<const short8*>(&QP[wq*16 + l16][g*8]);
        const short8 pa1 = *reinterpret_cast<const short8*>(&QP[wq*16 + l16][32 + g*8]);
#pragma unroll
        for (int df = 0; df < 4; ++df) {
            short8 vb0 = *reinterpret_cast<const short8*>(&Vt[df*16 + l16][g*8]);
            short8 vb1 = *reinterpret_cast<const short8*>(&Vt[df*16 + l16][32 + g*8]);
            Oacc[df] = __builtin_amdgcn_mfma_f32_16x16x32_bf16(pa0, vb0, Oacc[df], 0, 0, 0);
            Oacc[df] = __builtin_amdgcn_mfma_f32_16x16x32_bf16(pa1, vb1, Oacc[df], 0, 0, 0);
        }
    }

    // ---- normalize + store bf16
    float inv[4];
#pragma unroll
    for (int r = 0; r < 4; ++r) inv[r] = 1.0f / lrow[r];
#pragma unroll
    for (int df = 0; df < 4; ++df) {
#pragma unroll
        for (int r = 0; r < 4; ++r) {
            const int qg = q0 + wq * 16 + g * 4 + r;
            x[(size_t)(b * S_ + qg) * D_ + h * 64 + df * 16 + l16] = f2bf(Oacc[df][r] * inv[r]);
        }
    }
}

// ---------------------------------------------------------------------------
extern "C" void kernel_launch(void* const* d_in, const int* in_sizes, int n_in,
                              void* d_out, int out_size, void* d_ws, size_t ws_size,
                              hipStream_t stream) {
    const float* inputs = (const float*)d_in[0];
    const void*  mask   = d_in[1];
    const float* Wqkv   = (const float*)d_in[2];
    const float* bqkv   = (const float*)d_in[3];
    const float* Wproj  = (const float*)d_in[4];
    const float* bproj  = (const float*)d_in[5];
    float* out = (float*)d_out;

    // workspace layout (ushorts then floats):
    unsigned short* qkvb = (unsigned short*)d_ws;         // M*N3 bf16
    unsigned short* xb   = qkvb + (size_t)M_ * N3_;       // M*D  bf16
    unsigned short* Ab   = xb + (size_t)M_ * D_;          // M*D  bf16 (inputs)
    unsigned short* Wqb  = Ab + (size_t)M_ * D_;          // N3*D bf16
    unsigned short* Wpb  = Wqb + (size_t)N3_ * D_;        // D*D  bf16
    float* maskbias = (float*)(Wpb + (size_t)D_ * D_);    // M floats
    int*   flag     = (int*)(maskbias + M_);

    k_detect_mask<<<1, 256, 0, stream>>>((const unsigned char*)mask, flag);
    k_expand_mask<<<(M_ + 255) / 256, 256, 0, stream>>>(mask, flag, maskbias, M_);

    k_f2bf<<<(M_ * D_ / 4 + 255) / 256, 256, 0, stream>>>(inputs, Ab, M_ * D_);
    k_f2bf<<<(N3_ * D_ / 4 + 255) / 256, 256, 0, stream>>>(Wqkv, Wqb, N3_ * D_);
    k_f2bf<<<(D_ * D_ / 4 + 255) / 256, 256, 0, stream>>>(Wproj, Wpb, D_ * D_);

    dim3 g1(N3_ / 128, M_ / 128);   // 24 x 32
    k_gemm_bf16_nt<true><<<g1, 256, 0, stream>>>(Ab, Wqb, bqkv, qkvb, M_, N3_, D_);

    k_attn_mfma<<<B_ * H_ * (S_ / 64), 256, 0, stream>>>(qkvb, maskbias, xb);

    dim3 g2(D_ / 128, M_ / 128);    // 8 x 32
    k_gemm_bf16_nt<false><<<g2, 256, 0, stream>>>(xb, Wpb, bproj, out, M_, D_, D_);
}

// Round 4
// 194.153 us; speedup vs baseline: 9.3171x; 1.2105x over previous
//
#include <hip/hip_runtime.h>
#include <cstdint>
#include <cstddef>

// Problem constants (AltAttention: B=2, S=2048, D=1024, H=16, dh=64)
#define B_  2
#define S_  2048
#define D_  1024
#define H_  16
#define DH_ 64
#define M_  (B_*S_)     // 4096 rows
#define N3_ (3*D_)      // 3072 qkv cols
#define NT_ (S_/64)     // 32 key tiles

typedef float f32x4 __attribute__((ext_vector_type(4)));
typedef short short8 __attribute__((ext_vector_type(8)));
typedef unsigned short u16x8 __attribute__((ext_vector_type(8)));
typedef unsigned short u16x4 __attribute__((ext_vector_type(4)));

__device__ __forceinline__ unsigned short f2bf(float x) {
    unsigned int u = __float_as_uint(x);
    unsigned int r = (u + 0x7FFFu + ((u >> 16) & 1u)) >> 16;
    return (unsigned short)r;
}

__device__ __forceinline__ float exp2_(float x) { return __builtin_amdgcn_exp2f(x); }

__device__ __forceinline__ unsigned int cvt_pk_bf16(float a, float b) {
    unsigned int r;
    asm volatile("v_cvt_pk_bf16_f32 %0, %1, %2" : "=v"(r) : "v"(a), "v"(b));
    return r;
}

__device__ __forceinline__ void gload16(const void* g, void* l) {
    __builtin_amdgcn_global_load_lds(
        (const __attribute__((address_space(1))) unsigned int*)g,
        (__attribute__((address_space(3))) unsigned int*)l,
        16, 0, 0);
}

// ---------------------------------------------------------------------------
// Mask layout detection (verified rounds 1-3)
// ---------------------------------------------------------------------------
__global__ void k_detect_mask(const unsigned char* __restrict__ mb, int* __restrict__ flag) {
    __shared__ int sBig, sM4, sM8;
    if (threadIdx.x == 0) { sBig = 0; sM4 = 0; sM8 = 0; }
    __syncthreads();
    int big = 0, m4 = 0, m8 = 0;
    for (int i = threadIdx.x; i < 4096; i += blockDim.x) {
        unsigned char v = mb[i];
        if (v > 1) big = 1;
        if (v && (i & 3)) m4 = 1;
        if (v && ((i & 7) == 4)) m8 = 1;
    }
    if (big) atomicOr(&sBig, 1);
    if (m4)  atomicOr(&sM4, 1);
    if (m8)  atomicOr(&sM8, 1);
    __syncthreads();
    if (threadIdx.x == 0) {
        int w;
        if (sBig)      w = 0;
        else if (sM4)  w = 1;
        else if (sM8)  w = 4;
        else           w = 8;
        *flag = w;
    }
}

// One wave per 64-key tile -> uint64 bitmask via ballot.
__global__ void k_maskbits(const void* __restrict__ mask, const int* __restrict__ flag,
                           unsigned long long* __restrict__ bits) {
    int i = blockIdx.x * 64 + threadIdx.x;
    int w = *flag;
    bool on;
    if (w == 0)      on = ((const float*)mask)[i] != 0.0f;
    else if (w == 1) on = ((const unsigned char*)mask)[i] != 0;
    else if (w == 4) on = ((const int*)mask)[i] != 0;
    else             on = ((const long long*)mask)[i] != 0;
    unsigned long long bal = __ballot(on);
    if (threadIdx.x == 0) bits[blockIdx.x] = bal;
}

// ---------------------------------------------------------------------------
// fp32 -> bf16 convert (vectorized)
// ---------------------------------------------------------------------------
__global__ void k_f2bf(const float* __restrict__ in, unsigned short* __restrict__ out, int n) {
    int i = (blockIdx.x * blockDim.x + threadIdx.x) * 4;
    if (i >= n) return;
    float4 v = *reinterpret_cast<const float4*>(&in[i]);
    u16x4 o = { f2bf(v.x), f2bf(v.y), f2bf(v.z), f2bf(v.w) };
    *reinterpret_cast<u16x4*>(&out[i]) = o;
}

// ---------------------------------------------------------------------------
// bf16 MFMA GEMM (m97 structure, verified round 3)
// ---------------------------------------------------------------------------
template <bool OUT_BF16>
__global__ __launch_bounds__(256) void k_gemm_bf16_nt(
    const unsigned short* __restrict__ A, const unsigned short* __restrict__ W,
    const float* __restrict__ bias, void* __restrict__ Cout,
    int M, int N, int K) {
    __shared__ __align__(16) unsigned short Al[128 * 64];
    __shared__ __align__(16) unsigned short Wl[128 * 64];

    const int tid  = threadIdx.x;
    const int lane = tid & 63;
    const int w    = tid >> 6;
    const int wr   = w >> 1, wc = w & 1;
    const int l16  = lane & 15, g = lane >> 4;
    const int m0 = blockIdx.y * 128, n0 = blockIdx.x * 128;

    f32x4 acc[4][4];
#pragma unroll
    for (int m = 0; m < 4; ++m)
#pragma unroll
        for (int n = 0; n < 4; ++n) acc[m][n] = (f32x4){0.f, 0.f, 0.f, 0.f};

    const int srow = tid >> 3, scol = (tid & 7) * 8;

    for (int k0 = 0; k0 < K; k0 += 64) {
        __syncthreads();
#pragma unroll
        for (int i = 0; i < 4; ++i) {
            const int c = i * 256 + tid;
            const int row = srow + i * 32;
            gload16(A + (size_t)(m0 + row) * K + k0 + scol, Al + c * 8);
            gload16(W + (size_t)(n0 + row) * K + k0 + scol, Wl + c * 8);
        }
        __syncthreads();

#pragma unroll
        for (int kk = 0; kk < 2; ++kk) {
            short8 a[4], b[4];
#pragma unroll
            for (int m = 0; m < 4; ++m)
                a[m] = *reinterpret_cast<const short8*>(
                    &Al[(size_t)(wr * 64 + m * 16 + l16) * 64 + kk * 32 + g * 8]);
#pragma unroll
            for (int n = 0; n < 4; ++n)
                b[n] = *reinterpret_cast<const short8*>(
                    &Wl[(size_t)(wc * 64 + n * 16 + l16) * 64 + kk * 32 + g * 8]);
#pragma unroll
            for (int m = 0; m < 4; ++m)
#pragma unroll
                for (int n = 0; n < 4; ++n)
                    acc[m][n] = __builtin_amdgcn_mfma_f32_16x16x32_bf16(a[m], b[n], acc[m][n], 0, 0, 0);
        }
    }

    float bv[4];
#pragma unroll
    for (int n = 0; n < 4; ++n) bv[n] = bias[n0 + wc * 64 + n * 16 + l16];
#pragma unroll
    for (int m = 0; m < 4; ++m) {
#pragma unroll
        for (int r = 0; r < 4; ++r) {
            const size_t row = m0 + wr * 64 + m * 16 + g * 4 + r;
#pragma unroll
            for (int n = 0; n < 4; ++n) {
                const int col = n0 + wc * 64 + n * 16 + l16;
                float v = acc[m][n][r] + bv[n];
                if (OUT_BF16)
                    ((unsigned short*)Cout)[row * N + col] = f2bf(v);
                else
                    ((float*)Cout)[row * N + col] = v;
            }
        }
    }
}

// ---------------------------------------------------------------------------
// Flash attention, swapped-QK^T softmax, bf16 MFMA.
// Block = (b, h, 64 q-rows), 4 waves; wave owns 16 q-rows. K-tile = 64 keys.
// Swapped QK^T: ST = mfma(A=K_frag, B=Q_frag) -> lane holds 16 scores for
// q = l16 (keys jb*16 + g*4 + r). Row reduce = 15 local + 2 shfl.
// Mask: multiplicative via per-tile uint64 bitmask (max over masked scores
// is harmless since p is zeroed before sum/PV).
// Defer-max (THR=8 in log2 units): skip O-rescale while max growth small.
// Async-STAGE: next tile's K/V global loads issued right after LDS writes.
// ---------------------------------------------------------------------------
__global__ __launch_bounds__(256) void k_attn_mfma(
    const unsigned short* __restrict__ qkv,
    const unsigned long long* __restrict__ mbits,
    unsigned short* __restrict__ x) {
    __shared__ __align__(16) unsigned short Kt[64][72];
    __shared__ __align__(16) unsigned short Vt[64][72];
    __shared__ __align__(16) unsigned short QP[64][72];

    const int tid  = threadIdx.x;
    const int lane = tid & 63;
    const int wq   = tid >> 6;
    const int g    = lane >> 4;
    const int g4   = g * 4;
    const int l16  = lane & 15;

    const int nqt = S_ / 64;
    const int qt = blockIdx.x % nqt;
    const int h  = (blockIdx.x / nqt) % H_;
    const int b  = blockIdx.x / (nqt * H_);
    const int q0 = qt * 64;
    const size_t rowbase = (size_t)b * S_ * N3_;
    const int hq = h * 192, hk = hq + 64, hv = hq + 128;
    const unsigned short* kvb = qkv + rowbase;

    // ---- stage Q tile (64 x 64)
    {
        const int row = tid >> 2, cb = (tid & 3) * 16;
        const unsigned short* src = kvb + (size_t)(q0 + row) * N3_ + hq + cb;
        *reinterpret_cast<u16x8*>(&QP[row][cb])     = *reinterpret_cast<const u16x8*>(src);
        *reinterpret_cast<u16x8*>(&QP[row][cb + 8]) = *reinterpret_cast<const u16x8*>(src + 8);
    }
    __syncthreads();

    // Q fragments (identical layout works as A or B operand)
    const short8 qa0 = *reinterpret_cast<const short8*>(&QP[wq*16 + l16][g*8]);
    const short8 qa1 = *reinterpret_cast<const short8*>(&QP[wq*16 + l16][32 + g*8]);

    f32x4 Oacc[4];
#pragma unroll
    for (int df = 0; df < 4; ++df) Oacc[df] = (f32x4){0.f, 0.f, 0.f, 0.f};
    float m = -1e30f, l = 0.0f;

    const float LOG2E = 1.4426950408889634f;
    const float c1 = 0.03125f * LOG2E;                       // scale * log2e
    const float c2 = exp2f(-0.5f * (float)(h + 1)) * LOG2E;  // slope * log2e
    const int   qg = q0 + wq * 16 + l16;                     // this lane's q row
    float albr[4];
#pragma unroll
    for (int r = 0; r < 4; ++r) albr[r] = c2 * (float)(g4 + r);
    const float c2_16 = c2 * 16.0f;

    // staging geometry
    const int krow = tid >> 2, kcb = (tid & 3) * 16;
    const int vkb = (tid & 15) * 4, vdb = (tid >> 4) * 4;
    u16x8 kr0, kr1;
    u16x4 vr0, vr1, vr2, vr3;

    // preload tile 0
    {
        const unsigned short* ks = kvb + (size_t)krow * N3_ + hk + kcb;
        kr0 = *reinterpret_cast<const u16x8*>(ks);
        kr1 = *reinterpret_cast<const u16x8*>(ks + 8);
        const unsigned short* vs = kvb + (size_t)vkb * N3_ + hv + vdb;
        vr0 = *reinterpret_cast<const u16x4*>(vs);
        vr1 = *reinterpret_cast<const u16x4*>(vs + N3_);
        vr2 = *reinterpret_cast<const u16x4*>(vs + 2 * N3_);
        vr3 = *reinterpret_cast<const u16x4*>(vs + 3 * N3_);
    }

    for (int t = 0; t < NT_; ++t) {
        const int k0 = t * 64;
        __syncthreads();   // prior tile's LDS reads done

        // ---- write staged regs to LDS
        *reinterpret_cast<u16x8*>(&Kt[krow][kcb])     = kr0;
        *reinterpret_cast<u16x8*>(&Kt[krow][kcb + 8]) = kr1;
        {
            u16x4 w0 = { vr0.x, vr1.x, vr2.x, vr3.x };
            u16x4 w1 = { vr0.y, vr1.y, vr2.y, vr3.y };
            u16x4 w2 = { vr0.z, vr1.z, vr2.z, vr3.z };
            u16x4 w3 = { vr0.w, vr1.w, vr2.w, vr3.w };
            *reinterpret_cast<u16x4*>(&Vt[vdb + 0][vkb]) = w0;
            *reinterpret_cast<u16x4*>(&Vt[vdb + 1][vkb]) = w1;
            *reinterpret_cast<u16x4*>(&Vt[vdb + 2][vkb]) = w2;
            *reinterpret_cast<u16x4*>(&Vt[vdb + 3][vkb]) = w3;
        }
        // ---- issue next tile's loads (in flight during compute)
        if (t + 1 < NT_) {
            const int kn = k0 + 64;
            const unsigned short* ks = kvb + (size_t)(kn + krow) * N3_ + hk + kcb;
            kr0 = *reinterpret_cast<const u16x8*>(ks);
            kr1 = *reinterpret_cast<const u16x8*>(ks + 8);
            const unsigned short* vs = kvb + (size_t)(kn + vkb) * N3_ + hv + vdb;
            vr0 = *reinterpret_cast<const u16x4*>(vs);
            vr1 = *reinterpret_cast<const u16x4*>(vs + N3_);
            vr2 = *reinterpret_cast<const u16x4*>(vs + 2 * N3_);
            vr3 = *reinterpret_cast<const u16x4*>(vs + 3 * N3_);
        }
        __syncthreads();

        // ---- swapped QK^T: ST[jb] col=q(l16), row=key(jb*16+g4+r)
        float p_[4][4];
#pragma unroll
        for (int jb = 0; jb < 4; ++jb) {
            short8 kb0 = *reinterpret_cast<const short8*>(&Kt[jb*16 + l16][g*8]);
            short8 kb1 = *reinterpret_cast<const short8*>(&Kt[jb*16 + l16][32 + g*8]);
            f32x4 c = (f32x4){0.f, 0.f, 0.f, 0.f};
            c = __builtin_amdgcn_mfma_f32_16x16x32_bf16(kb0, qa0, c, 0, 0, 0);
            c = __builtin_amdgcn_mfma_f32_16x16x32_bf16(kb1, qa1, c, 0, 0, 0);
#pragma unroll
            for (int r = 0; r < 4; ++r) p_[jb][r] = c[r];
        }

        // ---- scores in log2 domain with 2-op alibi (uniform tile class)
        if (k0 < q0) {            // all keys <= q
            const float tb = c2 * (float)(k0 - qg);
#pragma unroll
            for (int jb = 0; jb < 4; ++jb) {
                const float tbj = tb + c2_16 * (float)jb;
#pragma unroll
                for (int r = 0; r < 4; ++r)
                    p_[jb][r] = fmaf(p_[jb][r], c1, tbj + albr[r]);
            }
        } else if (k0 > q0) {     // all keys >= q
            const float tb = c2 * (float)(k0 - qg);
#pragma unroll
            for (int jb = 0; jb < 4; ++jb) {
                const float tbj = -tb - c2_16 * (float)jb;
#pragma unroll
                for (int r = 0; r < 4; ++r)
                    p_[jb][r] = fmaf(p_[jb][r], c1, tbj - albr[r]);
            }
        } else {                  // diagonal tile
            const int dbase = k0 - qg;
#pragma unroll
            for (int jb = 0; jb < 4; ++jb)
#pragma unroll
                for (int r = 0; r < 4; ++r) {
                    int d = dbase + jb * 16 + g4 + r;
                    d = d < 0 ? -d : d;
                    p_[jb][r] = fmaf(p_[jb][r], c1, -c2 * (float)d);
                }
        }

        // ---- row max (masked scores included: harmless, p zeroed later)
        float mx = p_[0][0];
#pragma unroll
        for (int jb = 0; jb < 4; ++jb)
#pragma unroll
            for (int r = 0; r < 4; ++r) mx = fmaxf(mx, p_[jb][r]);
        mx = fmaxf(mx, __shfl_xor(mx, 16));
        mx = fmaxf(mx, __shfl_xor(mx, 32));

        // ---- defer-max rescale
        if (__any(mx > m + 8.0f)) {
            const float mn = fmaxf(m, mx);
            const float cr = exp2_(m - mn);
            m = mn;
            l *= cr;
            const int srcb = (lane & 48) + ((lane & 48) >> 2);
#pragma unroll
            for (int r = 0; r < 4; ++r) {
                const float crq = __shfl(cr, srcb + r);
#pragma unroll
                for (int df = 0; df < 4; ++df) Oacc[df][r] *= crq;
            }
        }

        // ---- exp + mask + sum
        const unsigned long long mb = mbits[b * NT_ + t];
        const unsigned long long msh = mb >> g4;
        const unsigned int mw0 = (unsigned int)msh;
        const unsigned int mw1 = (unsigned int)(msh >> 32);
        float ps = 0.0f;
#pragma unroll
        for (int jb = 0; jb < 4; ++jb)
#pragma unroll
            for (int r = 0; r < 4; ++r) {
                float p = exp2_(p_[jb][r] - m);
                const unsigned int w = (jb < 2) ? mw0 : mw1;
                const int idx = (jb & 1) * 16 + r;
                p = ((w >> idx) & 1u) ? p : 0.0f;
                p_[jb][r] = p;
                ps += p;
            }
        ps += __shfl_xor(ps, 16);
        ps += __shfl_xor(ps, 32);
        l += ps;

        // ---- pack P to bf16, write to per-wave LDS strip (same-wave read)
#pragma unroll
        for (int jb = 0; jb < 4; ++jb) {
            uint2 st;
            st.x = cvt_pk_bf16(p_[jb][0], p_[jb][1]);
            st.y = cvt_pk_bf16(p_[jb][2], p_[jb][3]);
            *reinterpret_cast<uint2*>(&QP[wq*16 + l16][jb*16 + g4]) = st;
        }

        // ---- PV: A = P, B = Vt
        const short8 pa0 = *reinterpret_cast<const short8*>(&QP[wq*16 + l16][g*8]);
        const short8 pa1 = *reinterpret_cast<const short8*>(&QP[wq*16 + l16][32 + g*8]);
#pragma unroll
        for (int df = 0; df < 4; ++df) {
            short8 vb0 = *reinterpret_cast<const short8*>(&Vt[df*16 + l16][g*8]);
            short8 vb1 = *reinterpret_cast<const short8*>(&Vt[df*16 + l16][32 + g*8]);
            Oacc[df] = __builtin_amdgcn_mfma_f32_16x16x32_bf16(pa0, vb0, Oacc[df], 0, 0, 0);
            Oacc[df] = __builtin_amdgcn_mfma_f32_16x16x32_bf16(pa1, vb1, Oacc[df], 0, 0, 0);
        }
    }

    // ---- normalize (l lives at lane l16=q; broadcast to output rows) + store
    const int srcb = (lane & 48) + ((lane & 48) >> 2);
    float invq[4];
#pragma unroll
    for (int r = 0; r < 4; ++r) invq[r] = 1.0f / __shfl(l, srcb + r);
#pragma unroll
    for (int df = 0; df < 4; ++df) {
#pragma unroll
        for (int r = 0; r < 4; ++r) {
            const int qrow = q0 + wq * 16 + g4 + r;
            x[(size_t)(b * S_ + qrow) * D_ + h * 64 + df * 16 + l16] = f2bf(Oacc[df][r] * invq[r]);
        }
    }
}

// ---------------------------------------------------------------------------
extern "C" void kernel_launch(void* const* d_in, const int* in_sizes, int n_in,
                              void* d_out, int out_size, void* d_ws, size_t ws_size,
                              hipStream_t stream) {
    const float* inputs = (const float*)d_in[0];
    const void*  mask   = d_in[1];
    const float* Wqkv   = (const float*)d_in[2];
    const float* bqkv   = (const float*)d_in[3];
    const float* Wproj  = (const float*)d_in[4];
    const float* bproj  = (const float*)d_in[5];
    float* out = (float*)d_out;

    // workspace layout
    unsigned short* qkvb = (unsigned short*)d_ws;         // M*N3 bf16
    unsigned short* xb   = qkvb + (size_t)M_ * N3_;       // M*D  bf16
    unsigned short* Ab   = xb + (size_t)M_ * D_;          // M*D  bf16 (inputs)
    unsigned short* Wqb  = Ab + (size_t)M_ * D_;          // N3*D bf16
    unsigned short* Wpb  = Wqb + (size_t)N3_ * D_;        // D*D  bf16
    unsigned long long* bits = (unsigned long long*)(Wpb + (size_t)D_ * D_);  // B*NT u64
    int* flag = (int*)(bits + B_ * NT_);

    k_detect_mask<<<1, 256, 0, stream>>>((const unsigned char*)mask, flag);
    k_maskbits<<<B_ * NT_, 64, 0, stream>>>(mask, flag, bits);

    k_f2bf<<<(M_ * D_ / 4 + 255) / 256, 256, 0, stream>>>(inputs, Ab, M_ * D_);
    k_f2bf<<<(N3_ * D_ / 4 + 255) / 256, 256, 0, stream>>>(Wqkv, Wqb, N3_ * D_);
    k_f2bf<<<(D_ * D_ / 4 + 255) / 256, 256, 0, stream>>>(Wproj, Wpb, D_ * D_);

    dim3 g1(N3_ / 128, M_ / 128);   // 24 x 32
    k_gemm_bf16_nt<true><<<g1, 256, 0, stream>>>(Ab, Wqb, bqkv, qkvb, M_, N3_, D_);

    k_attn_mfma<<<B_ * H_ * (S_ / 64), 256, 0, stream>>>(qkvb, bits, xb);

    dim3 g2(D_ / 128, M_ / 128);    // 8 x 32
    k_gemm_bf16_nt<false><<<g2, 256, 0, stream>>>(xb, Wpb, bproj, out, M_, D_, D_);
}